// Round 1
// 170.247 us; speedup vs baseline: 1.0070x; 1.0070x over previous
//
#include <hip/hip_runtime.h>

// FeynNet: out[b,o,p] = relu(bn2(conv(bn1(max(gather_a, gather_b)))))
// B=128, C=32, N=12, P=8192, M=2. Output 134 MB fp32 -> write floor ~21 us.
//
// R5: fp16 datapath + operand-swapped MFMA.
//  - feats staged in LDS as fp16 ONCE per block (384 cvt) instead of
//    per-position f2bf (256x128 cvt): gather is 16 ds_read_b128 + 48
//    v_pk_max_f16 per thread, result written to xh with no conversion
//    (RNE f32->f16 is monotone, so f16(max) == max(f16)).
//  - MFMA computes D[pos][o] = mfma(A=x_frag, B=W_frag). A/B fragments
//    have symmetric lane layouts (idx=lane&15, k=q*8+j) so register
//    contents are identical to the verified R3/R4 fragments; only the
//    operand order and epilogue indexing change. Each lane now holds 4
//    CONSECUTIVE positions of one output row -> 8 global_store_dwordx4
//    per thread instead of 32 scalar stores.
//  - W'' kept as f16 hi/lo (err ~2^-22); x err 2^-11 (was bf16 2^-8).
//  - bias fold parallelized: per-thread partials during w2 fold +
//    __shfl_xor half-wave reduction (removes 32-iter serial L2 loop).
// LDS de-conflict: fa/fb stride 40 ushorts (80 B: row bank starts
// {0,20,8,28,16,4,24,12,...} - max 2-way = free); xh keeps the R4
// slot-rotation swizzle (slot = (q + r + (r>>3)) & 3).

#define EPS 1e-5f
constexpr int B   = 128;
constexpr int C   = 32;
constexpr int NA  = 12;
constexpr int PP  = 8192;  // P
constexpr int PT  = 256;   // positions per block
constexpr int FS  = 40;    // fa/fb row stride (ushorts): 80 B, 16B-aligned
constexpr int XS  = 40;    // xh row stride (ushorts): 80 B, 16B-aligned
constexpr int W2S = 36;    // w2 row stride (floats): 144 B, 16B-aligned

typedef _Float16 f16x8 __attribute__((ext_vector_type(8)));
typedef float    f32x4 __attribute__((ext_vector_type(4)));

__device__ __forceinline__ uint pkmax(uint a, uint b) {   // 2x fp16 max
    uint d;
    asm("v_pk_max_f16 %0, %1, %2" : "=v"(d) : "v"(a), "v"(b));
    return d;
}

__global__ __launch_bounds__(256) void main_kernel(
    const float* __restrict__ feat_a, const float* __restrict__ feat_b,
    const int*   __restrict__ assign_a, const int* __restrict__ assign_b,
    const float* __restrict__ conv_w,
    const float* __restrict__ g1, const float* __restrict__ b1,
    const float* __restrict__ m1, const float* __restrict__ v1,
    const float* __restrict__ g2, const float* __restrict__ b2,
    const float* __restrict__ m2, const float* __restrict__ v2,
    float* __restrict__ out)
{
    __shared__ float s1[C], t1[C], s2v[C], bsh[C];
    __shared__ __align__(16) float     w2[C * W2S];
    __shared__ __align__(16) _Float16  fa[NA * FS];
    __shared__ __align__(16) _Float16  fb[NA * FS];
    __shared__ __align__(16) ushort    xh[PT * XS];

    const int tid  = threadIdx.x;
    const int lane = tid & 63;
    const int b    = blockIdx.x >> 5;          // 32 position-tiles per batch
    const int p0   = (blockIdx.x & 31) * PT;
    const int q    = lane >> 4;                // k-quad
    const int n    = lane & 15;                // M/N index within fragment

    // ---- Fold stage 1: BN scales + fp16 feat staging (independent) ----
    if (tid < C) {
        float s = g1[tid] * rsqrtf(v1[tid] + EPS);
        s1[tid]  = s;
        t1[tid]  = b1[tid] - m1[tid] * s;
        s2v[tid] = g2[tid] * rsqrtf(v2[tid] + EPS);
    }
    for (int i = tid; i < C * NA; i += 256) {   // fa[nn*FS+c] = f16(feat[b][c][nn])
        int c = i / NA, nn = i - c * NA;
        fa[nn * FS + c] = (_Float16)feat_a[b * C * NA + i];
        fb[nn * FS + c] = (_Float16)feat_b[b * C * NA + i];
    }
    __syncthreads();

    // ---- Fold stage 2: W''[o][c] (fp32, LDS) + bias''[o] (parallel) ----
    {
        float bpart[4];
#pragma unroll
        for (int it = 0; it < 4; ++it) {
            int i = tid + it * 256;
            int o = i >> 5, c = i & 31;
            float cw = conv_w[i];
            w2[o * W2S + c] = cw * s1[c] * s2v[o];
            bpart[it] = cw * t1[c];
        }
        // reduce over the 32 lanes sharing the same o (aligned half-wave)
#pragma unroll
        for (int m = 16; m >= 1; m >>= 1) {
#pragma unroll
            for (int it = 0; it < 4; ++it)
                bpart[it] += __shfl_xor(bpart[it], m, 64);
        }
        if ((tid & 31) == 0) {
            int o0 = tid >> 5;
#pragma unroll
            for (int it = 0; it < 4; ++it) {
                int o = o0 + it * 8;
                bsh[o] = bpart[it] * s2v[o] + (b2[o] - m2[o] * s2v[o]);
            }
        }
    }
    __syncthreads();

    // ---- W-fragments (f16 hi/lo) as MFMA *B* operands ----
    // B[k][o]: o = (lane&15)+16*tile, k = q*8+j  (same regs as verified R3 A-frag)
    f16x8 wh0, wl0, wh1, wl1;
    {
        float wv0[8], wv1[8];
        const float* r0 = &w2[n * W2S + q * 8];
        const float* r1 = &w2[(n + 16) * W2S + q * 8];
        *(float4*)&wv0[0] = *(const float4*)(r0);
        *(float4*)&wv0[4] = *(const float4*)(r0 + 4);
        *(float4*)&wv1[0] = *(const float4*)(r1);
        *(float4*)&wv1[4] = *(const float4*)(r1 + 4);
#pragma unroll
        for (int j = 0; j < 8; ++j) {
            _Float16 h0 = (_Float16)wv0[j];
            wh0[j] = h0;
            wl0[j] = (_Float16)(wv0[j] - (float)h0);
            _Float16 h1 = (_Float16)wv1[j];
            wh1[j] = h1;
            wl1[j] = (_Float16)(wv1[j] - (float)h1);
        }
    }
    const float bias_lo = bsh[n];
    const float bias_hi = bsh[16 + n];

    // ---- Phase 1: fp16 gather + 4-way packed max, swizzled LDS ----
    {
        const int p = p0 + tid;
        const int2 ia = ((const int2*)assign_a)[p];
        const int2 ib = ((const int2*)assign_b)[p];
        const _Float16* a0 = &fa[ia.x * FS];
        const _Float16* a1 = &fa[ia.y * FS];
        const _Float16* c0 = &fb[ib.x * FS];
        const _Float16* c1 = &fb[ib.y * FS];

        ushort* rowh = &xh[tid * XS];
        const int rot = (tid + (tid >> 3)) & 3;
#pragma unroll
        for (int g = 0; g < 4; ++g) {       // 8 channels per group
            uint4 va0 = *(const uint4*)(a0 + g * 8);
            uint4 va1 = *(const uint4*)(a1 + g * 8);
            uint4 vb0 = *(const uint4*)(c0 + g * 8);
            uint4 vb1 = *(const uint4*)(c1 + g * 8);
            uint4 m;
            m.x = pkmax(pkmax(va0.x, va1.x), pkmax(vb0.x, vb1.x));
            m.y = pkmax(pkmax(va0.y, va1.y), pkmax(vb0.y, vb1.y));
            m.z = pkmax(pkmax(va0.z, va1.z), pkmax(vb0.z, vb1.z));
            m.w = pkmax(pkmax(va0.w, va1.w), pkmax(vb0.w, vb1.w));
            *(uint4*)(rowh + ((g + rot) & 3) * 8) = m;
        }
    }
    __syncthreads();

    // ---- Phase 2: MFMA (D[pos][o]); wave w owns 16-pos chunks [4w, 4w+4) ----
    const int wave = tid >> 6;
    const f32x4 zero = {0.f, 0.f, 0.f, 0.f};
    float* outb = out + b * C * PP + p0;
#pragma unroll
    for (int ch = 0; ch < 4; ++ch) {
        const int base = (wave * 4 + ch) * 16;
        const int r    = base + n;                    // A-frag row = position
        const int slot = (q + r + (r >> 3)) & 3;
        const f16x8 xa = *(const f16x8*)&xh[r * XS + slot * 8];

        f32x4 d0 = __builtin_amdgcn_mfma_f32_16x16x32_f16(xa, wh0, zero, 0, 0, 0);
        d0       = __builtin_amdgcn_mfma_f32_16x16x32_f16(xa, wl0, d0,   0, 0, 0);
        f32x4 d1 = __builtin_amdgcn_mfma_f32_16x16x32_f16(xa, wh1, zero, 0, 0, 0);
        d1       = __builtin_amdgcn_mfma_f32_16x16x32_f16(xa, wl1, d1,   0, 0, 0);

        // lane holds positions base+q*4 .. +3 of rows o=n and o=n+16
        float* op = outb + base + q * 4;
        float4 v0, v1;
        v0.x = fmaxf(d0[0] + bias_lo, 0.f);
        v0.y = fmaxf(d0[1] + bias_lo, 0.f);
        v0.z = fmaxf(d0[2] + bias_lo, 0.f);
        v0.w = fmaxf(d0[3] + bias_lo, 0.f);
        v1.x = fmaxf(d1[0] + bias_hi, 0.f);
        v1.y = fmaxf(d1[1] + bias_hi, 0.f);
        v1.z = fmaxf(d1[2] + bias_hi, 0.f);
        v1.w = fmaxf(d1[3] + bias_hi, 0.f);
        *(float4*)(op + n * PP)        = v0;
        *(float4*)(op + (16 + n) * PP) = v1;
    }
}

extern "C" void kernel_launch(void* const* d_in, const int* in_sizes, int n_in,
                              void* d_out, int out_size, void* d_ws, size_t ws_size,
                              hipStream_t stream) {
    const float* feat_a   = (const float*)d_in[0];
    const float* feat_b   = (const float*)d_in[1];
    const int*   assign_a = (const int*)  d_in[2];
    const int*   assign_b = (const int*)  d_in[3];
    const float* g1 = (const float*)d_in[4];
    const float* b1 = (const float*)d_in[5];
    const float* m1 = (const float*)d_in[6];
    const float* v1 = (const float*)d_in[7];
    const float* cw = (const float*)d_in[8];
    const float* g2 = (const float*)d_in[9];
    const float* b2 = (const float*)d_in[10];
    const float* m2 = (const float*)d_in[11];
    const float* v2 = (const float*)d_in[12];

    float* out = (float*)d_out;
    (void)d_ws; (void)ws_size;

    main_kernel<<<B * (PP / PT), 256, 0, stream>>>(
        feat_a, feat_b, assign_a, assign_b, cw,
        g1, b1, m1, v1, g2, b2, m2, v2, out);
}